// Round 1
// baseline (1270.939 us; speedup 1.0000x reference)
//
#include <hip/hip_runtime.h>

// Problem constants (from reference): N=50000, F_IN=512, F_OUT=64, C=4, E=1.6M
#define F_IN 512
#define F_OUT 64

// ---------------------------------------------------------------------------
// Phase 1: s[n][c] = tanh(dot(x[n], core_w[c]) + core_b[c]), one wave per node
// ---------------------------------------------------------------------------
__global__ __launch_bounds__(256) void signal_kernel(
    const float* __restrict__ x, const float* __restrict__ core_w,
    const float* __restrict__ core_b, float* __restrict__ s, int N) {
  int wave = (int)((blockIdx.x * blockDim.x + threadIdx.x) >> 6);
  int lane = threadIdx.x & 63;
  if (wave >= N) return;

  const float4* xv = (const float4*)(x + (size_t)wave * F_IN);
  float4 a0 = xv[lane * 2];
  float4 a1 = xv[lane * 2 + 1];

  float p[4];
#pragma unroll
  for (int c = 0; c < 4; ++c) {
    const float4* wv = (const float4*)(core_w + c * F_IN);
    float4 w0 = wv[lane * 2];
    float4 w1 = wv[lane * 2 + 1];
    p[c] = a0.x * w0.x + a0.y * w0.y + a0.z * w0.z + a0.w * w0.w +
           a1.x * w1.x + a1.y * w1.y + a1.z * w1.z + a1.w * w1.w;
  }
  // wave64 tree reduce
#pragma unroll
  for (int off = 32; off > 0; off >>= 1) {
#pragma unroll
    for (int c = 0; c < 4; ++c) p[c] += __shfl_down(p[c], off, 64);
  }
  if (lane == 0) {
    float4 r;
    r.x = tanhf(p[0] + core_b[0]);
    r.y = tanhf(p[1] + core_b[1]);
    r.z = tanhf(p[2] + core_b[2]);
    r.w = tanhf(p[3] + core_b[3]);
    ((float4*)s)[wave] = r;
  }
}

// ---------------------------------------------------------------------------
// Phase 2: seg[tgt] += s[src]; cnt[tgt] += 1.   One thread per edge.
// seg/cnt are ~1 MB total -> L2-resident atomics.
// ---------------------------------------------------------------------------
__global__ __launch_bounds__(256) void scatter_kernel(
    const int* __restrict__ src, const int* __restrict__ tgt,
    const float* __restrict__ s, float* __restrict__ seg,
    float* __restrict__ cnt, int E) {
  int i = blockIdx.x * blockDim.x + threadIdx.x;
  if (i >= E) return;
  int u = src[i];
  int v = tgt[i];
  float4 sv = ((const float4*)s)[u];
  atomicAdd(&seg[(size_t)v * 4 + 0], sv.x);
  atomicAdd(&seg[(size_t)v * 4 + 1], sv.y);
  atomicAdd(&seg[(size_t)v * 4 + 2], sv.z);
  atomicAdd(&seg[(size_t)v * 4 + 3], sv.w);
  atomicAdd(&cnt[v], 1.0f);
}

// ---------------------------------------------------------------------------
// Phase 3: out[n,f,o] = relu(x[n,f] * t[n,o] + b_out[o]),
//          t[n,o] = sum_c avg[n,c] * W_out[o,c];  one block per node.
// 4096 f32 per node, written as 1024 coalesced float4.
// ---------------------------------------------------------------------------
__global__ __launch_bounds__(256) void out_kernel(
    const float* __restrict__ x, const float* __restrict__ seg,
    const float* __restrict__ cnt, const float* __restrict__ W_out,
    const float* __restrict__ b_out, float* __restrict__ out, int N) {
  int n = blockIdx.x;
  int tid = threadIdx.x;

  __shared__ float avg[4];
  __shared__ float xs[F_OUT];
  __shared__ float to[F_OUT];
  __shared__ float bo[F_OUT];

  if (tid < 4) {
    float c = cnt[n];
    avg[tid] = (c > 0.0f) ? seg[(size_t)n * 4 + tid] / c : 0.0f;
  }
  if (tid >= 64 && tid < 128) {
    int f = tid - 64;
    xs[f] = x[(size_t)n * F_IN + f];
  }
  __syncthreads();
  if (tid < 64) {
    to[tid] = avg[0] * W_out[tid * 4 + 0] + avg[1] * W_out[tid * 4 + 1] +
              avg[2] * W_out[tid * 4 + 2] + avg[3] * W_out[tid * 4 + 3];
    bo[tid] = b_out[tid];
  }
  __syncthreads();

  float4* ov = (float4*)(out + (size_t)n * (F_OUT * F_OUT));
#pragma unroll
  for (int it = 0; it < 4; ++it) {
    int slot = tid + it * 256;   // 0..1023 ; slot = f*16 + (o/4)
    int f = slot >> 4;
    int o4 = (slot & 15) * 4;
    float xf = xs[f];
    float4 r;
    r.x = fmaxf(xf * to[o4 + 0] + bo[o4 + 0], 0.0f);
    r.y = fmaxf(xf * to[o4 + 1] + bo[o4 + 1], 0.0f);
    r.z = fmaxf(xf * to[o4 + 2] + bo[o4 + 2], 0.0f);
    r.w = fmaxf(xf * to[o4 + 3] + bo[o4 + 3], 0.0f);
    ov[slot] = r;
  }
}

extern "C" void kernel_launch(void* const* d_in, const int* in_sizes, int n_in,
                              void* d_out, int out_size, void* d_ws, size_t ws_size,
                              hipStream_t stream) {
  const float* x      = (const float*)d_in[0];
  const int*   eidx   = (const int*)d_in[1];
  const float* core_w = (const float*)d_in[2];
  const float* core_b = (const float*)d_in[3];
  const float* W_out  = (const float*)d_in[4];
  const float* b_out  = (const float*)d_in[5];
  float* out = (float*)d_out;

  const int N = in_sizes[0] / F_IN;     // 50000
  const int E = in_sizes[1] / 2;        // 1600000
  const int* src = eidx;
  const int* tgt = eidx + E;

  // Workspace layout: [seg: N*4 f32][cnt: N f32][s: N*4 f32]
  float* seg = (float*)d_ws;
  float* cnt = seg + (size_t)N * 4;
  float* s   = cnt + (size_t)N;        // byte offset N*20 = 1,000,000 (16B aligned)

  // zero the accumulators (ws is poisoned 0xAA before every launch)
  hipMemsetAsync(seg, 0, (size_t)N * 5 * sizeof(float), stream);

  {
    int waves_per_block = 4;  // 256 threads
    int blocks = (N + waves_per_block - 1) / waves_per_block;
    signal_kernel<<<blocks, 256, 0, stream>>>(x, core_w, core_b, s, N);
  }
  {
    int blocks = (E + 255) / 256;
    scatter_kernel<<<blocks, 256, 0, stream>>>(src, tgt, s, seg, cnt, E);
  }
  {
    out_kernel<<<N, 256, 0, stream>>>(x, seg, cnt, W_out, b_out, out, N);
  }
}